// Round 1
// baseline (688.117 us; speedup 1.0000x reference)
//
#include <hip/hip_runtime.h>

// Problem constants (from reference):
//   B=256, C=8, M=16, N=4096, R=D=64, CM=C*M=128
//   outputs[b,n] = sum_cm x[b,cm,n] * w[cm]          (4 MiB out, 512 MiB in)
//   idx = argmax_n outputs[b,:]  (first-max tiebreak)
//   r = trunc(r_target[idx/64]); d = trunc(d_target[idx%64])
//   flat out = [outputs (B*N), d (B), r (B), d (B)]

#define BATCH   256
#define NDIM    4096
#define CM      128
#define NT      4            // n-tiles per batch row
#define TILE_N  1024         // NDIM / NT
#define THREADS 256

__global__ __launch_bounds__(THREADS) void conv_argmax_kernel(
    const float* __restrict__ x, const float* __restrict__ W,
    float* __restrict__ out, float* __restrict__ wval, int* __restrict__ widx)
{
    __shared__ float w[CM];
    __shared__ float sval[THREADS / 64];
    __shared__ int   sidx[THREADS / 64];

    const int blk  = blockIdx.x;        // 0 .. BATCH*NT-1
    const int b    = blk >> 2;          // / NT
    const int tile = blk & (NT - 1);
    const int tid  = threadIdx.x;

    if (tid < CM) w[tid] = W[tid];
    __syncthreads();

    const int n0 = tile * TILE_N + tid * 4;
    const float* xp = x + (size_t)b * CM * NDIM + n0;

    float acc0 = 0.f, acc1 = 0.f, acc2 = 0.f, acc3 = 0.f;
    #pragma unroll 8
    for (int cm = 0; cm < CM; ++cm) {
        float4 v = *(const float4*)(xp + (size_t)cm * NDIM);
        float wc = w[cm];
        acc0 += v.x * wc;
        acc1 += v.y * wc;
        acc2 += v.z * wc;
        acc3 += v.w * wc;
    }
    float4 o = make_float4(acc0, acc1, acc2, acc3);
    *(float4*)(out + (size_t)b * NDIM + n0) = o;

    // Local argmax over this thread's 4 outputs (ascending index, strict > ==
    // first-occurrence tiebreak like jnp.argmax).
    float bv = acc0; int bi = n0;
    if (acc1 > bv) { bv = acc1; bi = n0 + 1; }
    if (acc2 > bv) { bv = acc2; bi = n0 + 2; }
    if (acc3 > bv) { bv = acc3; bi = n0 + 3; }

    // Wave (64-lane) reduction: larger value wins; equal value -> smaller index.
    for (int off = 32; off >= 1; off >>= 1) {
        float ov = __shfl_down(bv, off, 64);
        int   oi = __shfl_down(bi, off, 64);
        if (ov > bv || (ov == bv && oi < bi)) { bv = ov; bi = oi; }
    }
    const int wave = tid >> 6;
    if ((tid & 63) == 0) { sval[wave] = bv; sidx[wave] = bi; }
    __syncthreads();
    if (tid == 0) {
        for (int i = 1; i < THREADS / 64; ++i) {
            if (sval[i] > bv || (sval[i] == bv && sidx[i] < bi)) {
                bv = sval[i]; bi = sidx[i];
            }
        }
        wval[blk] = bv;
        widx[blk] = bi;
    }
}

__global__ __launch_bounds__(BATCH) void finalize_kernel(
    const float* __restrict__ wval, const int* __restrict__ widx,
    const float* __restrict__ r_target, const float* __restrict__ d_target,
    float* __restrict__ out)
{
    const int b = threadIdx.x;   // one thread per batch row
    float bv = wval[b * NT];
    int   bi = widx[b * NT];
    #pragma unroll
    for (int t = 1; t < NT; ++t) {
        float v = wval[b * NT + t];
        int   i = widx[b * NT + t];
        if (v > bv || (v == bv && i < bi)) { bv = v; bi = i; }
    }
    const int r_index = bi >> 6;          // idx // 64  (len_r == 64)
    const int d_index = bi & 63;          // idx - (idx//64)*64  (len_d == 64)
    // Reference assigns float into int tensor: truncation toward zero.
    const float r = (float)(int)r_target[r_index];
    const float d = (float)(int)d_target[d_index];
    const int BN = BATCH * NDIM;
    out[BN + b]              = d;   // second return element: d
    out[BN + BATCH + b]      = r;   // output tuple: r
    out[BN + 2 * BATCH + b]  = d;   // output tuple: d
}

extern "C" void kernel_launch(void* const* d_in, const int* in_sizes, int n_in,
                              void* d_out, int out_size, void* d_ws, size_t ws_size,
                              hipStream_t stream) {
    const float* x        = (const float*)d_in[0];  // [B, C, M, N] = [256,8,16,4096]
    const float* W        = (const float*)d_in[1];  // [1, C, M, 1] -> 128 floats, idx c*16+m
    const float* r_target = (const float*)d_in[2];  // [64]
    const float* d_target = (const float*)d_in[3];  // [64]
    float* out = (float*)d_out;

    float* wval = (float*)d_ws;                     // BATCH*NT floats
    int*   widx = (int*)((float*)d_ws + BATCH * NT);

    conv_argmax_kernel<<<BATCH * NT, THREADS, 0, stream>>>(x, W, out, wval, widx);
    finalize_kernel<<<1, BATCH, 0, stream>>>(wval, widx, r_target, d_target, out);
}

// Round 3
// 644.067 us; speedup vs baseline: 1.0684x; 1.0684x over previous
//
#include <hip/hip_runtime.h>

// Problem constants (from reference):
//   B=256, C=8, M=16, N=4096, R=D=64, CM=C*M=128
//   outputs[b,n] = sum_cm x[b,cm,n] * w[cm]          (4 MiB out, 512 MiB in)
//   idx = argmax_n outputs[b,:]  (first-max tiebreak)
//   r = trunc(r_target[idx/64]); d = trunc(d_target[idx%64])
//   flat out = [outputs (B*N), d (B), r (B), d (B)]

#define BATCH   256
#define NDIM    4096
#define CM      128
#define NT      4            // n-tiles per batch row
#define TILE_N  1024         // NDIM / NT
#define THREADS 256

typedef float v4f __attribute__((ext_vector_type(4)));  // clang-native for nontemporal builtin

__global__ __launch_bounds__(THREADS) void conv_argmax_kernel(
    const float* __restrict__ x, const float* __restrict__ W,
    float* __restrict__ out, float* __restrict__ wval, int* __restrict__ widx)
{
    __shared__ float w[CM];
    __shared__ float sval[THREADS / 64];
    __shared__ int   sidx[THREADS / 64];

    // Tile-major ordering: consecutive blockIdx -> different b (2 MiB apart)
    // for better DRAM channel/bank spread among co-resident blocks.
    const int blk  = blockIdx.x;        // 0 .. BATCH*NT-1
    const int b    = blk & (BATCH - 1);
    const int tile = blk >> 8;          // / BATCH
    const int tid  = threadIdx.x;

    if (tid < CM) w[tid] = W[tid];
    __syncthreads();

    const int n0 = tile * TILE_N + tid * 4;
    const float* xp = x + (size_t)b * CM * NDIM + n0;

    float acc0 = 0.f, acc1 = 0.f, acc2 = 0.f, acc3 = 0.f;
    // 8 chunks of 16: up to 16 global_load_dwordx4 in flight per wave.
    #pragma unroll 2
    for (int chunk = 0; chunk < CM; chunk += 16) {
        v4f v[16];
        #pragma unroll
        for (int j = 0; j < 16; ++j) {
            v[j] = __builtin_nontemporal_load(
                (const v4f*)(xp + (size_t)(chunk + j) * NDIM));
        }
        #pragma unroll
        for (int j = 0; j < 16; ++j) {
            const float wc = w[chunk + j];
            acc0 += v[j].x * wc;
            acc1 += v[j].y * wc;
            acc2 += v[j].z * wc;
            acc3 += v[j].w * wc;
        }
    }
    float4 o = make_float4(acc0, acc1, acc2, acc3);
    *(float4*)(out + (size_t)b * NDIM + n0) = o;

    // Local argmax over this thread's 4 outputs (ascending index, strict > ==
    // first-occurrence tiebreak like jnp.argmax).
    float bv = acc0; int bi = n0;
    if (acc1 > bv) { bv = acc1; bi = n0 + 1; }
    if (acc2 > bv) { bv = acc2; bi = n0 + 2; }
    if (acc3 > bv) { bv = acc3; bi = n0 + 3; }

    // Wave (64-lane) reduction: larger value wins; equal value -> smaller index.
    for (int off = 32; off >= 1; off >>= 1) {
        float ov = __shfl_down(bv, off, 64);
        int   oi = __shfl_down(bi, off, 64);
        if (ov > bv || (ov == bv && oi < bi)) { bv = ov; bi = oi; }
    }
    const int wave = tid >> 6;
    if ((tid & 63) == 0) { sval[wave] = bv; sidx[wave] = bi; }
    __syncthreads();
    if (tid == 0) {
        for (int i = 1; i < THREADS / 64; ++i) {
            if (sval[i] > bv || (sval[i] == bv && sidx[i] < bi)) {
                bv = sval[i]; bi = sidx[i];
            }
        }
        // ws layout indexed by (b, tile) so finalize reads are contiguous per b.
        wval[b * NT + tile] = bv;
        widx[b * NT + tile] = bi;
    }
}

__global__ __launch_bounds__(BATCH) void finalize_kernel(
    const float* __restrict__ wval, const int* __restrict__ widx,
    const float* __restrict__ r_target, const float* __restrict__ d_target,
    float* __restrict__ out)
{
    const int b = threadIdx.x;   // one thread per batch row
    float bv = wval[b * NT];
    int   bi = widx[b * NT];
    #pragma unroll
    for (int t = 1; t < NT; ++t) {
        float v = wval[b * NT + t];
        int   i = widx[b * NT + t];
        if (v > bv || (v == bv && i < bi)) { bv = v; bi = i; }
    }
    const int r_index = bi >> 6;          // idx // 64  (len_r == 64)
    const int d_index = bi & 63;          // idx - (idx//64)*64  (len_d == 64)
    // Reference assigns float into int tensor: truncation toward zero.
    const float r = (float)(int)r_target[r_index];
    const float d = (float)(int)d_target[d_index];
    const int BN = BATCH * NDIM;
    out[BN + b]              = d;   // second return element: d
    out[BN + BATCH + b]      = r;   // output tuple: r
    out[BN + 2 * BATCH + b]  = d;   // output tuple: d
}

extern "C" void kernel_launch(void* const* d_in, const int* in_sizes, int n_in,
                              void* d_out, int out_size, void* d_ws, size_t ws_size,
                              hipStream_t stream) {
    const float* x        = (const float*)d_in[0];  // [B, C, M, N] = [256,8,16,4096]
    const float* W        = (const float*)d_in[1];  // [1, C, M, 1] -> 128 floats, idx c*16+m
    const float* r_target = (const float*)d_in[2];  // [64]
    const float* d_target = (const float*)d_in[3];  // [64]
    float* out = (float*)d_out;

    float* wval = (float*)d_ws;                     // BATCH*NT floats
    int*   widx = (int*)((float*)d_ws + BATCH * NT);

    conv_argmax_kernel<<<BATCH * NT, THREADS, 0, stream>>>(x, W, out, wval, widx);
    finalize_kernel<<<1, BATCH, 0, stream>>>(wval, widx, r_target, d_target, out);
}

// Round 4
// 641.742 us; speedup vs baseline: 1.0723x; 1.0036x over previous
//
#include <hip/hip_runtime.h>

// Problem constants (from reference):
//   B=256, C=8, M=16, N=4096, R=D=64, CM=C*M=128
//   outputs[b,n] = sum_cm x[b,cm,n] * w[cm]          (4 MiB out, 512 MiB in)
//   idx = argmax_n outputs[b,:]  (first-max tiebreak)
//   r = trunc(r_target[idx/64]); d = trunc(d_target[idx%64])
//   flat out = [outputs (B*N), d (B), r (B), d (B)]
//
// Single kernel: one 1024-thread block per batch row (256 blocks = 1/CU).
// Each block streams full contiguous 16 KiB x-rows, computes the row argmax
// internally, and writes its own tail outputs — no finalize kernel, no ws.

#define BATCH   256
#define NDIM    4096
#define CM      128
#define THREADS 1024
#define NWAVES  (THREADS / 64)

typedef float v4f __attribute__((ext_vector_type(4)));  // clang-native for nontemporal builtin

__global__ __launch_bounds__(THREADS, 4) void conv_argmax_kernel(
    const float* __restrict__ x, const float* __restrict__ W,
    const float* __restrict__ r_target, const float* __restrict__ d_target,
    float* __restrict__ out)
{
    __shared__ float w[CM];
    __shared__ float sval[NWAVES];
    __shared__ int   sidx[NWAVES];

    const int b   = blockIdx.x;
    const int tid = threadIdx.x;

    if (tid < CM) w[tid] = W[tid];
    __syncthreads();

    const int n0 = tid * 4;                       // this thread's 4 columns
    const float* xp = x + (size_t)b * CM * NDIM + n0;

    float acc0 = 0.f, acc1 = 0.f, acc2 = 0.f, acc3 = 0.f;
    // 8 chunks of 16: up to 16 global_load_dwordx4 in flight per wave.
    #pragma unroll 2
    for (int chunk = 0; chunk < CM; chunk += 16) {
        v4f v[16];
        #pragma unroll
        for (int j = 0; j < 16; ++j) {
            v[j] = __builtin_nontemporal_load(
                (const v4f*)(xp + (size_t)(chunk + j) * NDIM));
        }
        #pragma unroll
        for (int j = 0; j < 16; ++j) {
            const float wc = w[chunk + j];
            acc0 += v[j].x * wc;
            acc1 += v[j].y * wc;
            acc2 += v[j].z * wc;
            acc3 += v[j].w * wc;
        }
    }
    *(float4*)(out + (size_t)b * NDIM + n0) = make_float4(acc0, acc1, acc2, acc3);

    // Thread-local argmax (ascending index => first-occurrence tiebreak,
    // matching jnp.argmax).
    float bv = acc0; int bi = n0;
    if (acc1 > bv) { bv = acc1; bi = n0 + 1; }
    if (acc2 > bv) { bv = acc2; bi = n0 + 2; }
    if (acc3 > bv) { bv = acc3; bi = n0 + 3; }

    // Wave (64-lane) reduction: larger value wins; equal value -> smaller index.
    for (int off = 32; off >= 1; off >>= 1) {
        float ov = __shfl_down(bv, off, 64);
        int   oi = __shfl_down(bi, off, 64);
        if (ov > bv || (ov == bv && oi < bi)) { bv = ov; bi = oi; }
    }
    const int wave = tid >> 6;
    if ((tid & 63) == 0) { sval[wave] = bv; sidx[wave] = bi; }
    __syncthreads();

    if (tid == 0) {
        #pragma unroll
        for (int i = 1; i < NWAVES; ++i) {
            if (sval[i] > bv || (sval[i] == bv && sidx[i] < bi)) {
                bv = sval[i]; bi = sidx[i];
            }
        }
        const int r_index = bi >> 6;      // idx // 64  (len_r == 64)
        const int d_index = bi & 63;      // idx % 64   (len_d == 64)
        // Reference assigns float into int tensor: truncation toward zero.
        const float r = (float)(int)r_target[r_index];
        const float d = (float)(int)d_target[d_index];
        const int BN = BATCH * NDIM;
        out[BN + b]             = d;      // second return element: d
        out[BN + BATCH + b]     = r;      // output tuple: r
        out[BN + 2 * BATCH + b] = d;      // output tuple: d
    }
}

extern "C" void kernel_launch(void* const* d_in, const int* in_sizes, int n_in,
                              void* d_out, int out_size, void* d_ws, size_t ws_size,
                              hipStream_t stream) {
    const float* x        = (const float*)d_in[0];  // [B, C, M, N] = [256,8,16,4096]
    const float* W        = (const float*)d_in[1];  // [1, C, M, 1] -> 128 floats, idx c*16+m
    const float* r_target = (const float*)d_in[2];  // [64]
    const float* d_target = (const float*)d_in[3];  // [64]
    float* out = (float*)d_out;

    conv_argmax_kernel<<<BATCH, THREADS, 0, stream>>>(x, W, r_target, d_target, out);
}